// Round 1
// baseline (7331.120 us; speedup 1.0000x reference)
//
#include <hip/hip_runtime.h>
#include <math.h>

// Problem constants
#define T_     8
#define WQ_    75
#define C_     640
#define HW_    100
#define WAY_   5
#define SHOT_  5
#define SHW_   500      // SHOT*HW
#define ROWS_  7500     // WQ*HW  (rows per (t,w) GEMM)
#define EPSN   1e-12f

// ---------------------------------------------------------------------------
// qinv[t][q][c] = 1 / max(||query[t,q,c,:]||_2, eps)   (norm over hw)
// ---------------------------------------------------------------------------
__global__ __launch_bounds__(256) void qnorm_kernel(const float* __restrict__ query,
                                                    float* __restrict__ qinv) {
    int tq = blockIdx.x;                    // 0..599  (t*75+q)
    const float* base = query + (size_t)tq * C_ * HW_;
    int lane = threadIdx.x & 63;
    int wv   = threadIdx.x >> 6;            // 0..3
    for (int c = wv; c < C_; c += 4) {
        const float* pc = base + (size_t)c * HW_;
        float v0 = pc[lane];                              // lane < 64 < 100
        float v1 = (lane + 64 < HW_) ? pc[lane + 64] : 0.f;
        float ssq = v0 * v0 + v1 * v1;
        #pragma unroll
        for (int o = 32; o; o >>= 1) ssq += __shfl_xor(ssq, o);
        if (lane == 0)
            qinv[(size_t)tq * C_ + c] = 1.f / fmaxf(sqrtf(ssq), EPSN);
    }
}

// ---------------------------------------------------------------------------
// sinv[t][w][k] = 1 / max(||support[t, w*5+s, :, p]||_2, eps)  (norm over c)
//   k = s*100 + p
// ---------------------------------------------------------------------------
__global__ __launch_bounds__(256) void snorm_kernel(const float* __restrict__ sup,
                                                    float* __restrict__ sinv) {
    __shared__ float part[4][64];
    int g0   = blockIdx.x * 64;             // first flat idx of this block
    int lane = threadIdx.x & 63;
    int wv   = threadIdx.x >> 6;
    int idx  = g0 + lane;                   // (t*25+u)*100 + p
    float ssq = 0.f;
    if (idx < T_ * 25 * HW_) {
        int tu = idx / HW_, p = idx % HW_;
        const float* base = sup + (size_t)tu * C_ * HW_ + p;
        #pragma unroll 4
        for (int c = wv * 160; c < wv * 160 + 160; ++c) {
            float x = base[(size_t)c * HW_];
            ssq = fmaf(x, x, ssq);
        }
    }
    part[wv][lane] = ssq;
    __syncthreads();
    if (wv == 0 && idx < T_ * 25 * HW_) {
        float s = part[0][lane] + part[1][lane] + part[2][lane] + part[3][lane];
        int tu = idx / HW_, p = idx % HW_;
        int u = tu % 25, t = tu / 25;
        int w = u / 5, sh = u % 5;
        sinv[(((size_t)t * WAY_ + w) * SHOT_ + sh) * HW_ + p] =
            1.f / fmaxf(sqrtf(s), EPSN);
    }
}

// ---------------------------------------------------------------------------
// Main: per (t,w) GEMM rel = Qn (7500x640) * Sn (640x500), fused top-3 per
// row, atomicAdd into score[t][q][w].
// Tile: BM=16 rows, BN=512 cols (500 real), BK=16. 256 threads.
// Thread: 8 rows x 4 cols outer product (rg = tid>>7 in {0,1}, cg = tid&127).
// ---------------------------------------------------------------------------
__global__ __launch_bounds__(256) void dn4_main(const float* __restrict__ query,
                                                const float* __restrict__ sup,
                                                const float* __restrict__ qinv,
                                                const float* __restrict__ sinv,
                                                float* __restrict__ score) {
    __shared__ float As[16][16];    // [c][r]
    __shared__ float Bs[16][512];   // [c][k]   (reused for rel tile in epilogue)

    const int tw = blockIdx.y;
    const int t = tw / WAY_, w = tw % WAY_;
    const int r0 = blockIdx.x * 16;
    const int tid = threadIdx.x;
    const int rg = tid >> 7;        // 0..1
    const int cg = tid & 127;       // 0..127

    const float* qT  = query + (size_t)t * WQ_ * C_ * HW_;
    const float* qiT = qinv  + (size_t)t * WQ_ * C_;
    const float* sW  = sup   + ((size_t)t * 25 + (size_t)w * SHOT_) * C_ * HW_;
    const float* siW = sinv  + (size_t)(t * WAY_ + w) * SHW_;

    // --- hoisted staging addresses ---
    // A-tile element for this thread: c_local = tid>>4, row r0 + (tid&15)
    const int a_cl = tid >> 4;
    const int a_rl = tid & 15;
    const int a_r  = r0 + a_rl;
    const bool a_ok = (a_r < ROWS_);
    int a_q = 0, a_p = 0;
    if (a_ok) { a_q = a_r / HW_; a_p = a_r - a_q * HW_; }
    const size_t a_base = ((size_t)a_q * C_) * HW_ + a_p;

    // B-tile: this thread stages k0 = tid and k1 = tid+256 for each of 16 c's
    const int k0 = tid;             // < 256 < 500, always valid
    const int k1 = tid + 256;       // valid iff < 500
    const bool k1ok = (k1 < SHW_);
    const int  s0 = k0 / HW_, p0 = k0 - s0 * HW_;
    const int  s1 = k1 / HW_, p1 = k1 - s1 * HW_;
    const size_t b_base0 = (size_t)s0 * C_ * HW_ + p0;
    const size_t b_base1 = (size_t)s1 * C_ * HW_ + p1;
    const float si0 = siW[k0];
    const float si1 = k1ok ? siW[k1] : 0.f;

    float acc[8][4];
    #pragma unroll
    for (int i = 0; i < 8; ++i)
        #pragma unroll
        for (int j = 0; j < 4; ++j) acc[i][j] = 0.f;

    for (int c0 = 0; c0 < C_; c0 += 16) {
        // stage A (16x16)
        {
            int c = c0 + a_cl;
            float v = 0.f;
            if (a_ok) v = qT[a_base + (size_t)c * HW_] * qiT[a_q * C_ + c];
            As[a_cl][a_rl] = v;
        }
        // stage B (16x512, 2 elements/thread/c)
        #pragma unroll
        for (int c = 0; c < 16; ++c) {
            size_t coff = (size_t)(c0 + c) * HW_;
            Bs[c][k0] = sW[b_base0 + coff] * si0;
            Bs[c][k1] = k1ok ? sW[b_base1 + coff] * si1 : 0.f;
        }
        __syncthreads();

        #pragma unroll
        for (int kk = 0; kk < 16; ++kk) {
            float4 a0 = *(const float4*)&As[kk][rg * 8];
            float4 a1 = *(const float4*)&As[kk][rg * 8 + 4];
            float4 b0 = *(const float4*)&Bs[kk][cg * 4];
            float a[8] = {a0.x, a0.y, a0.z, a0.w, a1.x, a1.y, a1.z, a1.w};
            float b[4] = {b0.x, b0.y, b0.z, b0.w};
            #pragma unroll
            for (int i = 0; i < 8; ++i)
                #pragma unroll
                for (int j = 0; j < 4; ++j)
                    acc[i][j] = fmaf(a[i], b[j], acc[i][j]);
        }
        __syncthreads();
    }

    // --- epilogue: dump rel tile into Bs, then top-3 per row ---
    #pragma unroll
    for (int i = 0; i < 8; ++i) {
        float4 v = make_float4(acc[i][0], acc[i][1], acc[i][2], acc[i][3]);
        *(float4*)&Bs[rg * 8 + i][cg * 4] = v;
    }
    __syncthreads();

    const int lane = tid & 63, wv = tid >> 6;
    #pragma unroll
    for (int ri = 0; ri < 4; ++ri) {
        int row = wv * 4 + ri;
        int r = r0 + row;
        if (r < ROWS_) {
            float v[8];
            #pragma unroll
            for (int j = 0; j < 8; ++j) {
                int col = lane + 64 * j;
                v[j] = (col < SHW_) ? Bs[row][col] : -INFINITY;
            }
            float ssum = 0.f;
            #pragma unroll
            for (int it = 0; it < 3; ++it) {
                float lm = v[0];
                #pragma unroll
                for (int j = 1; j < 8; ++j) lm = fmaxf(lm, v[j]);
                float gm = lm;
                #pragma unroll
                for (int o = 32; o; o >>= 1) gm = fmaxf(gm, __shfl_xor(gm, o));
                ssum += gm;
                unsigned long long mb = __ballot(lm == gm);
                int first = (int)__builtin_ctzll(mb);
                if (lane == first) {
                    bool done = false;
                    #pragma unroll
                    for (int j = 0; j < 8; ++j) {
                        if (!done && v[j] == gm) { v[j] = -INFINITY; done = true; }
                    }
                }
            }
            if (lane == 0) {
                int q = r / HW_;
                atomicAdd(&score[((size_t)t * WQ_ + q) * WAY_ + w], ssum);
            }
        }
    }
}

// ---------------------------------------------------------------------------
extern "C" void kernel_launch(void* const* d_in, const int* in_sizes, int n_in,
                              void* d_out, int out_size, void* d_ws, size_t ws_size,
                              hipStream_t stream) {
    const float* query   = (const float*)d_in[0];   // (8,75,640,10,10)
    const float* support = (const float*)d_in[1];   // (8,25,640,10,10)
    float* qinv = (float*)d_ws;                     // 8*75*640   = 384000 floats
    float* sinv = qinv + (size_t)T_ * WQ_ * C_;     // 8*5*500    = 20000 floats
    float* score = (float*)d_out;                   // 8*75*5     = 3000 floats

    hipMemsetAsync(d_out, 0, (size_t)out_size * sizeof(float), stream);

    hipLaunchKernelGGL(qnorm_kernel, dim3(T_ * WQ_), dim3(256), 0, stream,
                       query, qinv);
    hipLaunchKernelGGL(snorm_kernel, dim3((T_ * 25 * HW_ + 63) / 64), dim3(256),
                       0, stream, support, sinv);
    hipLaunchKernelGGL(dn4_main, dim3((ROWS_ + 15) / 16, T_ * WAY_), dim3(256),
                       0, stream, query, support, qinv, sinv, score);
}

// Round 5
// 1208.029 us; speedup vs baseline: 6.0687x; 6.0687x over previous
//
#include <hip/hip_runtime.h>
#include <math.h>

#define T_     8
#define WQ_    75
#define C_     640
#define HW_    100
#define WAY_   5
#define SHW_   500
#define ROWS_  7500
#define EPSN   1e-12f
#define NINF   (-__builtin_inff())

typedef __bf16 bf16_t;
typedef __bf16 bf16x8 __attribute__((ext_vector_type(8)));
typedef float  f32x4  __attribute__((ext_vector_type(4)));

__device__ __forceinline__ void gld16(const bf16_t* g, bf16_t* l) {
    __builtin_amdgcn_global_load_lds(
        (const __attribute__((address_space(1))) unsigned int*)g,
        (__attribute__((address_space(3))) unsigned int*)l, 16, 0, 0);
}

// sorted-triple merge: (a1>=a2>=a3) U (b1>=b2>=b3) -> top3
#define MERGE3(a1,a2,a3,b1,b2,b3)                       \
    {                                                   \
        float o1_ = fmaxf(a1,b1), c1_ = fminf(a1,b1);   \
        float h2_ = fmaxf(a2,b2), l2_ = fminf(a2,b2);   \
        float h3_ = fmaxf(a3,b3);                       \
        a1 = o1_;                                       \
        float n2_ = fmaxf(c1_, h2_);                    \
        a3 = fmaxf(fmaxf(l2_, h3_), fminf(c1_, h2_));   \
        a2 = n2_;                                       \
    }

// ---------------------------------------------------------------------------
// Qn[t][q*100+p][c] = query[t,q,c,p] / max(||query[t,q,c,:]||, eps)   (bf16)
// ---------------------------------------------------------------------------
__global__ __launch_bounds__(256) void qprep(const float* __restrict__ query,
                                             bf16_t* __restrict__ Qn) {
    int tq = blockIdx.x;                     // 0..599
    const float* src = query + (size_t)tq * C_ * HW_;
    bf16_t* dst = Qn + (size_t)tq * HW_ * C_;
    __shared__ float inv[C_];
    int tid = threadIdx.x;
    for (int c = tid; c < C_; c += 256) {
        const float* pc = src + (size_t)c * HW_;
        float s0=0,s1=0,s2=0,s3=0;
        for (int p = 0; p < HW_; p += 4) {
            s0 = fmaf(pc[p],   pc[p],   s0);
            s1 = fmaf(pc[p+1], pc[p+1], s1);
            s2 = fmaf(pc[p+2], pc[p+2], s2);
            s3 = fmaf(pc[p+3], pc[p+3], s3);
        }
        inv[c] = 1.f / fmaxf(sqrtf((s0+s1)+(s2+s3)), EPSN);
    }
    __syncthreads();
    for (int o = tid; o < HW_*C_; o += 256) {
        int p = o / C_, c = o - p*C_;
        dst[o] = (bf16_t)(src[(size_t)c*HW_ + p] * inv[c]);
    }
}

// ---------------------------------------------------------------------------
// Sn[t][u*100+p][c] = sup[t,u,c,p] / max(||sup[t,u,:,p]||, eps)       (bf16)
// (u = w*5+s, so row n = w*500 + s*100 + p)
// ---------------------------------------------------------------------------
__global__ __launch_bounds__(256) void sprep(const float* __restrict__ sup,
                                             bf16_t* __restrict__ Sn) {
    int tu = blockIdx.x;                     // 0..199
    const float* src = sup + (size_t)tu * C_ * HW_;
    bf16_t* dst = Sn + (size_t)tu * HW_ * C_;
    __shared__ float inv[HW_];
    int tid = threadIdx.x;
    if (tid < HW_) {
        float s0=0,s1=0,s2=0,s3=0;
        for (int c = 0; c < C_; c += 4) {
            float x0 = src[(size_t)c*HW_ + tid];
            float x1 = src[(size_t)(c+1)*HW_ + tid];
            float x2 = src[(size_t)(c+2)*HW_ + tid];
            float x3 = src[(size_t)(c+3)*HW_ + tid];
            s0=fmaf(x0,x0,s0); s1=fmaf(x1,x1,s1);
            s2=fmaf(x2,x2,s2); s3=fmaf(x3,x3,s3);
        }
        inv[tid] = 1.f / fmaxf(sqrtf((s0+s1)+(s2+s3)), EPSN);
    }
    __syncthreads();
    for (int o = tid; o < HW_*C_; o += 256) {
        int p = o / C_, c = o - p*C_;
        dst[o] = (bf16_t)(src[(size_t)c*HW_ + p] * inv[p]);
    }
}

// ---------------------------------------------------------------------------
// Main MFMA kernel: per (row-tile, t, w): rel tile (64 x 512[500]) over K=640,
// fused per-row top-3 + atomicAdd into score.
// 256 threads = 4 waves, wave tile 64x128 (4 M-frags x 8 N-frags, 16x16x32).
// LDS linear (global_load_lds); 16B-slot XOR swizzle on source+read.
// ---------------------------------------------------------------------------
__global__ __launch_bounds__(256) void dn4_mfma(const bf16_t* __restrict__ Qn,
                                                const bf16_t* __restrict__ Sn,
                                                float* __restrict__ score) {
    __shared__ bf16_t As[64 * 32];           // 4 KB
    __shared__ bf16_t Bs[512 * 32];          // 32 KB
    __shared__ float  topL[64][4][3];        // 3 KB

    const int t = blockIdx.y, w = blockIdx.z;
    const int rbase = blockIdx.x * 64;
    const int tid = threadIdx.x;
    const int l = tid & 63, wid = tid >> 6;  // 4 waves
    const int fr = l & 15, fq = l >> 4;
    const int wc = wid;                      // wave col 0..3 (wr == 0)

    const bf16_t* Qt = Qn + (size_t)t * ROWS_ * C_;
    const bf16_t* St = Sn + ((size_t)t * 2500 + (size_t)w * SHW_) * C_;

    // ---- staging addressing (LDS dest linear: waveBase + lane*16B) ----
    // A: wave wid stages LDS rows wid*16 .. +15 (64B per row)
    const int arow = (wid << 4) + (l >> 2);          // LDS A row 0..63
    const int aswz = (l & 3) ^ ((arow >> 1) & 3);    // source slot permutation
    int agr = rbase + arow; if (agr > ROWS_ - 1) agr = ROWS_ - 1;
    const bf16_t* asrc = Qt + (size_t)agr * C_ + aswz * 8;
    bf16_t* aldst = As + wid * 512;                  // wave-uniform

    // B: wave wid stages chunks (wid*8+j), j=0..7 -> n rows 0..511
    const int bswz = (l & 3) ^ ((l >> 3) & 3);       // (bn>>1)&3 == (l>>3)&3
    int bgo[8];
    #pragma unroll
    for (int j = 0; j < 8; ++j) {
        int n = wid * 128 + j * 16 + (l >> 2);
        if (n > SHW_ - 1) n = SHW_ - 1;              // clamp pad rows
        bgo[j] = n * C_ + bswz * 8;                  // elem offset into St
    }

    // ---- fragment LDS offsets (kt-invariant) ----
    int aoff[4], boff[8];
    #pragma unroll
    for (int mi = 0; mi < 4; ++mi) {
        int row = mi * 16 + fr;
        int slot = fq ^ ((row >> 1) & 3);
        aoff[mi] = row * 32 + slot * 8;
    }
    #pragma unroll
    for (int ni = 0; ni < 8; ++ni) {
        int n = wc * 128 + ni * 16 + fr;
        int slot = fq ^ ((n >> 1) & 3);
        boff[ni] = n * 32 + slot * 8;
    }

    f32x4 acc[4][8];
    #pragma unroll
    for (int mi = 0; mi < 4; ++mi)
        #pragma unroll
        for (int ni = 0; ni < 8; ++ni)
            acc[mi][ni] = (f32x4){0.f, 0.f, 0.f, 0.f};

    for (int kt = 0; kt < C_ / 32; ++kt) {
        const int ko = kt * 32;
        gld16(asrc + ko, aldst);
        #pragma unroll
        for (int j = 0; j < 8; ++j)
            gld16(St + bgo[j] + ko, Bs + (wid * 8 + j) * 512);
        __syncthreads();

        bf16x8 av[4], bv[8];
        #pragma unroll
        for (int mi = 0; mi < 4; ++mi) av[mi] = *(const bf16x8*)(As + aoff[mi]);
        #pragma unroll
        for (int ni = 0; ni < 8; ++ni) bv[ni] = *(const bf16x8*)(Bs + boff[ni]);

        #pragma unroll
        for (int mi = 0; mi < 4; ++mi)
            #pragma unroll
            for (int ni = 0; ni < 8; ++ni)
                acc[mi][ni] = __builtin_amdgcn_mfma_f32_16x16x32_bf16(
                    av[mi], bv[ni], acc[mi][ni], 0, 0, 0);
        __syncthreads();
    }

    // ---- fused top-3 epilogue ----
    // C/D layout: col = ni*16 + fr, row = mi*16 + fq*4 + j
    #pragma unroll
    for (int mi = 0; mi < 4; ++mi) {
        #pragma unroll
        for (int j = 0; j < 4; ++j) {
            float t1 = NINF, t2 = NINF, t3 = NINF;
            #pragma unroll
            for (int ni = 0; ni < 8; ++ni) {
                int gc = wc * 128 + ni * 16 + fr;
                float v = (gc < SHW_) ? acc[mi][ni][j] : NINF;
                float m1 = fmaxf(t1, v),  n1 = fminf(t1, v);
                float m2 = fmaxf(t2, n1), n2 = fminf(t2, n1);
                t1 = m1; t2 = m2; t3 = fmaxf(t3, n2);
            }
            #pragma unroll
            for (int d = 1; d < 16; d <<= 1) {
                float b1 = __shfl_xor(t1, d);
                float b2 = __shfl_xor(t2, d);
                float b3 = __shfl_xor(t3, d);
                MERGE3(t1, t2, t3, b1, b2, b3);
            }
            if (fr == 0) {
                int lrow = mi * 16 + fq * 4 + j;
                topL[lrow][wc][0] = t1;
                topL[lrow][wc][1] = t2;
                topL[lrow][wc][2] = t3;
            }
        }
    }
    __syncthreads();

    if (tid < 64) {
        float a1 = topL[tid][0][0], a2 = topL[tid][0][1], a3 = topL[tid][0][2];
        #pragma unroll
        for (int g = 1; g < 4; ++g) {
            float b1 = topL[tid][g][0], b2 = topL[tid][g][1], b3 = topL[tid][g][2];
            MERGE3(a1, a2, a3, b1, b2, b3);
        }
        int r = rbase + tid;
        if (r < ROWS_) {
            int q = r / 100;
            atomicAdd(score + ((size_t)(t * WQ_ + q) * WAY_ + w), a1 + a2 + a3);
        }
    }
}

// ---------------------------------------------------------------------------
extern "C" void kernel_launch(void* const* d_in, const int* in_sizes, int n_in,
                              void* d_out, int out_size, void* d_ws, size_t ws_size,
                              hipStream_t stream) {
    const float* query   = (const float*)d_in[0];   // (8,75,640,10,10)
    const float* support = (const float*)d_in[1];   // (8,25,640,10,10)
    bf16_t* Qn = (bf16_t*)d_ws;                     // 60000 x 640 bf16 = 76.8 MB
    bf16_t* Sn = Qn + (size_t)T_ * ROWS_ * C_;      // 20000 x 640 bf16 = 25.6 MB
    float* score = (float*)d_out;                   // 8*75*5

    hipMemsetAsync(d_out, 0, (size_t)out_size * sizeof(float), stream);

    hipLaunchKernelGGL(qprep, dim3(T_ * WQ_), dim3(256), 0, stream, query, Qn);
    hipLaunchKernelGGL(sprep, dim3(T_ * 25), dim3(256), 0, stream, support, Sn);
    hipLaunchKernelGGL(dn4_mfma, dim3((ROWS_ + 63) / 64, T_, WAY_), dim3(256),
                       0, stream, Qn, Sn, score);
}

// Round 6
// 726.063 us; speedup vs baseline: 10.0971x; 1.6638x over previous
//
#include <hip/hip_runtime.h>
#include <math.h>

#define T_     8
#define WQ_    75
#define C_     640
#define HW_    100
#define WAY_   5
#define SHW_   500
#define ROWS_  7500
#define EPSN   1e-12f
#define NINF   (-__builtin_inff())

typedef __bf16 bf16_t;
typedef __bf16 bf16x2 __attribute__((ext_vector_type(2)));
typedef __bf16 bf16x8 __attribute__((ext_vector_type(8)));
typedef float  f32x4  __attribute__((ext_vector_type(4)));

__device__ __forceinline__ void gld16(const bf16_t* g, bf16_t* l) {
    __builtin_amdgcn_global_load_lds(
        (const __attribute__((address_space(1))) unsigned int*)g,
        (__attribute__((address_space(3))) unsigned int*)l, 16, 0, 0);
}

// sorted-triple merge: (a1>=a2>=a3) U (b1>=b2>=b3) -> top3
#define MERGE3(a1,a2,a3,b1,b2,b3)                       \
    {                                                   \
        float o1_ = fmaxf(a1,b1), c1_ = fminf(a1,b1);   \
        float h2_ = fmaxf(a2,b2), l2_ = fminf(a2,b2);   \
        float h3_ = fmaxf(a3,b3);                       \
        a1 = o1_;                                       \
        float n2_ = fmaxf(c1_, h2_);                    \
        a3 = fmaxf(fmaxf(l2_, h3_), fminf(c1_, h2_));   \
        a2 = n2_;                                       \
    }

// ---------------------------------------------------------------------------
// qprep: Qn[t][q*100+p][c] = query[t,q,c,p] * qinv  (norm over hw, per c)
// Chunked LDS transpose: stage 128x100 f32 coalesced (float4; 100%4==0 so a
// float4 never crosses a row), rows padded to 101 (bank stride 5, no
// conflicts), norms from LDS, coalesced bf16x2 transposed store.
// ---------------------------------------------------------------------------
__global__ __launch_bounds__(256) void qprep(const float* __restrict__ query,
                                             bf16_t* __restrict__ Qn) {
    int tq = blockIdx.x;                     // 0..599
    const float* src = query + (size_t)tq * C_ * HW_;
    bf16_t* dst = Qn + (size_t)tq * HW_ * C_;
    __shared__ float tile[128 * 101];        // 51.7 KB
    __shared__ float invc[128];
    const int tid = threadIdx.x;

    for (int c0 = 0; c0 < C_; c0 += 128) {
        const float4* s4 = (const float4*)(src + (size_t)c0 * HW_);
        for (int j = tid; j < 3200; j += 256) {       // 128*100/4
            float4 v = s4[j];
            int f = j * 4;
            int c = f / 100, p = f - c * 100;
            float* d = &tile[c * 101 + p];
            d[0] = v.x; d[1] = v.y; d[2] = v.z; d[3] = v.w;
        }
        __syncthreads();
        if (tid < 128) {
            float s = 0.f;
            #pragma unroll 4
            for (int p = 0; p < HW_; ++p) {
                float x = tile[tid * 101 + p];
                s = fmaf(x, x, s);
            }
            invc[tid] = 1.f / fmaxf(sqrtf(s), EPSN);
        }
        __syncthreads();
        for (int j = tid; j < 6400; j += 256) {       // 100 p * 64 pairs
            int p  = j >> 6;
            int cl = (j & 63) * 2;
            bf16x2 v;
            v.x = (bf16_t)(tile[cl * 101 + p] * invc[cl]);
            v.y = (bf16_t)(tile[(cl + 1) * 101 + p] * invc[cl + 1]);
            *(bf16x2*)(dst + (size_t)p * C_ + c0 + cl) = v;
        }
        __syncthreads();
    }
}

// ---------------------------------------------------------------------------
// sprep: Sn[t][u*100+p][c] = sup[t,u,c,p] * sinv  (norm over c, per p)
// Phase A: coalesced norm pass (lanes span p). Phase B: chunked LDS
// transpose identical to qprep but scaled by invp[p].
// ---------------------------------------------------------------------------
__global__ __launch_bounds__(256) void sprep(const float* __restrict__ sup,
                                             bf16_t* __restrict__ Sn) {
    int tu = blockIdx.x;                     // 0..199
    const float* src = sup + (size_t)tu * C_ * HW_;
    bf16_t* dst = Sn + (size_t)tu * HW_ * C_;
    __shared__ float tile[128 * 101];
    __shared__ float invp[HW_];
    const int tid = threadIdx.x;

    if (tid < HW_) {
        float s0=0,s1=0,s2=0,s3=0;
        for (int c = 0; c < C_; c += 4) {
            float x0 = src[(size_t)c*HW_ + tid];
            float x1 = src[(size_t)(c+1)*HW_ + tid];
            float x2 = src[(size_t)(c+2)*HW_ + tid];
            float x3 = src[(size_t)(c+3)*HW_ + tid];
            s0=fmaf(x0,x0,s0); s1=fmaf(x1,x1,s1);
            s2=fmaf(x2,x2,s2); s3=fmaf(x3,x3,s3);
        }
        invp[tid] = 1.f / fmaxf(sqrtf((s0+s1)+(s2+s3)), EPSN);
    }
    __syncthreads();

    for (int c0 = 0; c0 < C_; c0 += 128) {
        const float4* s4 = (const float4*)(src + (size_t)c0 * HW_);
        for (int j = tid; j < 3200; j += 256) {
            float4 v = s4[j];
            int f = j * 4;
            int c = f / 100, p = f - c * 100;
            float* d = &tile[c * 101 + p];
            d[0] = v.x; d[1] = v.y; d[2] = v.z; d[3] = v.w;
        }
        __syncthreads();
        for (int j = tid; j < 6400; j += 256) {
            int p  = j >> 6;
            int cl = (j & 63) * 2;
            float iv = invp[p];
            bf16x2 v;
            v.x = (bf16_t)(tile[cl * 101 + p] * iv);
            v.y = (bf16_t)(tile[(cl + 1) * 101 + p] * iv);
            *(bf16x2*)(dst + (size_t)p * C_ + c0 + cl) = v;
        }
        __syncthreads();
    }
}

// ---------------------------------------------------------------------------
// Main MFMA kernel: per (row-tile, t, w): rel tile (64 x 512[500]) over K=640,
// fused per-row top-3 + atomicAdd into score.
// 2-phase double-buffered pipeline (T3 minimum): STAGE(next) issued BEFORE
// ds_read+MFMA(current); single barrier per K-step so the vmcnt(0) drain
// overlaps with 32 MFMAs instead of serializing.
// ---------------------------------------------------------------------------
__global__ __launch_bounds__(256) void dn4_mfma(const bf16_t* __restrict__ Qn,
                                                const bf16_t* __restrict__ Sn,
                                                float* __restrict__ score) {
    __shared__ bf16_t As[2][64 * 32];        // 8 KB
    __shared__ bf16_t Bs[2][512 * 32];       // 64 KB
    __shared__ float  topL[64][4][3];        // 3 KB

    const int t = blockIdx.y, w = blockIdx.z;
    const int rbase = blockIdx.x * 64;
    const int tid = threadIdx.x;
    const int l = tid & 63, wid = tid >> 6;  // 4 waves
    const int fr = l & 15, fq = l >> 4;
    const int wc = wid;                      // wave col 0..3

    const bf16_t* Qt = Qn + (size_t)t * ROWS_ * C_;
    const bf16_t* St = Sn + ((size_t)t * 2500 + (size_t)w * SHW_) * C_;

    // ---- staging addressing (LDS dest linear: waveBase + lane*16B) ----
    const int arow = (wid << 4) + (l >> 2);          // LDS A row 0..63
    const int aswz = (l & 3) ^ ((arow >> 1) & 3);    // source slot swizzle
    int agr = rbase + arow; if (agr > ROWS_ - 1) agr = ROWS_ - 1;
    const bf16_t* asrc = Qt + (size_t)agr * C_ + aswz * 8;

    const int bswz = (l & 3) ^ ((l >> 3) & 3);
    int bgo[8];
    #pragma unroll
    for (int j = 0; j < 8; ++j) {
        int n = wid * 128 + j * 16 + (l >> 2);
        if (n > SHW_ - 1) n = SHW_ - 1;
        bgo[j] = n * C_ + bswz * 8;
    }

    // ---- fragment LDS offsets (kt-invariant) ----
    int aoff[4], boff[8];
    #pragma unroll
    for (int mi = 0; mi < 4; ++mi) {
        int row = mi * 16 + fr;
        int slot = fq ^ ((row >> 1) & 3);
        aoff[mi] = row * 32 + slot * 8;
    }
    #pragma unroll
    for (int ni = 0; ni < 8; ++ni) {
        int n = wc * 128 + ni * 16 + fr;
        int slot = fq ^ ((n >> 1) & 3);
        boff[ni] = n * 32 + slot * 8;
    }

    f32x4 acc[4][8];
    #pragma unroll
    for (int mi = 0; mi < 4; ++mi)
        #pragma unroll
        for (int ni = 0; ni < 8; ++ni)
            acc[mi][ni] = (f32x4){0.f, 0.f, 0.f, 0.f};

    // prologue: stage tile 0 into buf 0
    {
        gld16(asrc, As[0] + wid * 512);
        #pragma unroll
        for (int j = 0; j < 8; ++j)
            gld16(St + bgo[j], Bs[0] + (wid * 8 + j) * 512);
    }
    __syncthreads();

    int cur = 0;
    for (int kt = 0; kt < C_ / 32; ++kt) {
        // issue next-tile prefetch (overlaps with this tile's MFMAs)
        if (kt + 1 < C_ / 32) {
            const int ko = (kt + 1) * 32;
            gld16(asrc + ko, As[cur ^ 1] + wid * 512);
            #pragma unroll
            for (int j = 0; j < 8; ++j)
                gld16(St + bgo[j] + ko, Bs[cur ^ 1] + (wid * 8 + j) * 512);
        }

        bf16x8 av[4], bv[8];
        #pragma unroll
        for (int mi = 0; mi < 4; ++mi)
            av[mi] = *(const bf16x8*)(As[cur] + aoff[mi]);
        #pragma unroll
        for (int ni = 0; ni < 8; ++ni)
            bv[ni] = *(const bf16x8*)(Bs[cur] + boff[ni]);

        #pragma unroll
        for (int mi = 0; mi < 4; ++mi)
            #pragma unroll
            for (int ni = 0; ni < 8; ++ni)
                acc[mi][ni] = __builtin_amdgcn_mfma_f32_16x16x32_bf16(
                    av[mi], bv[ni], acc[mi][ni], 0, 0, 0);

        __syncthreads();   // drains prefetch (vmcnt 0) + readers done
        cur ^= 1;
    }

    // ---- fused top-3 epilogue ----
    // C/D layout: col = ni*16 + fr, row = mi*16 + fq*4 + j
    #pragma unroll
    for (int mi = 0; mi < 4; ++mi) {
        #pragma unroll
        for (int j = 0; j < 4; ++j) {
            float t1 = NINF, t2 = NINF, t3 = NINF;
            #pragma unroll
            for (int ni = 0; ni < 8; ++ni) {
                int gc = wc * 128 + ni * 16 + fr;
                float v = (gc < SHW_) ? acc[mi][ni][j] : NINF;
                float m1 = fmaxf(t1, v),  n1 = fminf(t1, v);
                float m2 = fmaxf(t2, n1), n2 = fminf(t2, n1);
                t1 = m1; t2 = m2; t3 = fmaxf(t3, n2);
            }
            #pragma unroll
            for (int d = 1; d < 16; d <<= 1) {
                float b1 = __shfl_xor(t1, d);
                float b2 = __shfl_xor(t2, d);
                float b3 = __shfl_xor(t3, d);
                MERGE3(t1, t2, t3, b1, b2, b3);
            }
            if (fr == 0) {
                int lrow = mi * 16 + fq * 4 + j;
                topL[lrow][wc][0] = t1;
                topL[lrow][wc][1] = t2;
                topL[lrow][wc][2] = t3;
            }
        }
    }
    __syncthreads();

    if (tid < 64) {
        float a1 = topL[tid][0][0], a2 = topL[tid][0][1], a3 = topL[tid][0][2];
        #pragma unroll
        for (int g = 1; g < 4; ++g) {
            float b1 = topL[tid][g][0], b2 = topL[tid][g][1], b3 = topL[tid][g][2];
            MERGE3(a1, a2, a3, b1, b2, b3);
        }
        int r = rbase + tid;
        if (r < ROWS_) {
            int q = r / 100;
            atomicAdd(score + ((size_t)(t * WQ_ + q) * WAY_ + w), a1 + a2 + a3);
        }
    }
}

// ---------------------------------------------------------------------------
extern "C" void kernel_launch(void* const* d_in, const int* in_sizes, int n_in,
                              void* d_out, int out_size, void* d_ws, size_t ws_size,
                              hipStream_t stream) {
    const float* query   = (const float*)d_in[0];   // (8,75,640,10,10)
    const float* support = (const float*)d_in[1];   // (8,25,640,10,10)
    bf16_t* Qn = (bf16_t*)d_ws;                     // 60000 x 640 bf16 = 76.8 MB
    bf16_t* Sn = Qn + (size_t)T_ * ROWS_ * C_;      // 20000 x 640 bf16 = 25.6 MB
    float* score = (float*)d_out;                   // 8*75*5

    hipMemsetAsync(d_out, 0, (size_t)out_size * sizeof(float), stream);

    hipLaunchKernelGGL(qprep, dim3(T_ * WQ_), dim3(256), 0, stream, query, Qn);
    hipLaunchKernelGGL(sprep, dim3(T_ * 25), dim3(256), 0, stream, support, Sn);
    hipLaunchKernelGGL(dn4_mfma, dim3((ROWS_ + 63) / 64, T_, WAY_), dim3(256),
                       0, stream, Qn, Sn, score);
}

// Round 7
// 717.376 us; speedup vs baseline: 10.2194x; 1.0121x over previous
//
#include <hip/hip_runtime.h>
#include <math.h>

#define T_     8
#define WQ_    75
#define C_     640
#define HW_    100
#define WAY_   5
#define SHW_   500
#define ROWS_  7500
#define EPSN   1e-12f
#define NINF   (-__builtin_inff())

typedef __bf16 bf16_t;
typedef __bf16 bf16x2 __attribute__((ext_vector_type(2)));
typedef __bf16 bf16x8 __attribute__((ext_vector_type(8)));
typedef float  f32x4  __attribute__((ext_vector_type(4)));

__device__ __forceinline__ void gld16(const bf16_t* g, bf16_t* l) {
    __builtin_amdgcn_global_load_lds(
        (const __attribute__((address_space(1))) unsigned int*)g,
        (__attribute__((address_space(3))) unsigned int*)l, 16, 0, 0);
}

// sorted-triple merge: (a1>=a2>=a3) U (b1>=b2>=b3) -> top3
#define MERGE3(a1,a2,a3,b1,b2,b3)                       \
    {                                                   \
        float o1_ = fmaxf(a1,b1), c1_ = fminf(a1,b1);   \
        float h2_ = fmaxf(a2,b2), l2_ = fminf(a2,b2);   \
        float h3_ = fmaxf(a3,b3);                       \
        a1 = o1_;                                       \
        float n2_ = fmaxf(c1_, h2_);                    \
        a3 = fmaxf(fmaxf(l2_, h3_), fminf(c1_, h2_));   \
        a2 = n2_;                                       \
    }

// ---------------------------------------------------------------------------
// qprep: Qn[t][q*100+p][c] = query[t,q,c,p] * qinv  (norm over hw, per c)
// 512 threads. Chunked LDS transpose (128c x 100p, rows padded to 101).
// Norm phase uses all threads: 4 lanes per c, shfl_xor combine.
// ---------------------------------------------------------------------------
__global__ __launch_bounds__(512) void qprep(const float* __restrict__ query,
                                             bf16_t* __restrict__ Qn) {
    int tq = blockIdx.x;                     // 0..599
    const float* src = query + (size_t)tq * C_ * HW_;
    bf16_t* dst = Qn + (size_t)tq * HW_ * C_;
    __shared__ float tile[128 * 101];        // 51.7 KB
    __shared__ float invc[128];
    const int tid = threadIdx.x;

    for (int c0 = 0; c0 < C_; c0 += 128) {
        const float4* s4 = (const float4*)(src + (size_t)c0 * HW_);
        for (int j = tid; j < 3200; j += 512) {       // 128*100/4
            float4 v = s4[j];
            int f = j * 4;
            int c = f / 100, p = f - c * 100;
            float* d = &tile[c * 101 + p];
            d[0] = v.x; d[1] = v.y; d[2] = v.z; d[3] = v.w;
        }
        __syncthreads();
        {
            int c = tid >> 2, g = tid & 3;            // 4 lanes per c
            float s = 0.f;
            #pragma unroll 5
            for (int p = g * 25; p < g * 25 + 25; ++p) {
                float x = tile[c * 101 + p];
                s = fmaf(x, x, s);
            }
            s += __shfl_xor(s, 1);
            s += __shfl_xor(s, 2);
            if (g == 0) invc[c] = 1.f / fmaxf(sqrtf(s), EPSN);
        }
        __syncthreads();
        for (int j = tid; j < 6400; j += 512) {       // 100 p * 64 c-pairs
            int p  = j >> 6;
            int cl = (j & 63) * 2;
            bf16x2 v;
            v.x = (bf16_t)(tile[cl * 101 + p] * invc[cl]);
            v.y = (bf16_t)(tile[(cl + 1) * 101 + p] * invc[cl + 1]);
            *(bf16x2*)(dst + (size_t)p * C_ + c0 + cl) = v;
        }
        __syncthreads();
    }
}

// ---------------------------------------------------------------------------
// sprep: Sn[t][u*100+p][c] = sup[t,u,c,p] * sinv  (norm over c, per p)
// Phase A: 8 waves split the c-range (coalesced), LDS partials, combine.
// Phase B: chunked LDS transpose as qprep, scaled by invp[p].
// ---------------------------------------------------------------------------
__global__ __launch_bounds__(512) void sprep(const float* __restrict__ sup,
                                             bf16_t* __restrict__ Sn) {
    int tu = blockIdx.x;                     // 0..199
    const float* src = sup + (size_t)tu * C_ * HW_;
    bf16_t* dst = Sn + (size_t)tu * HW_ * C_;
    __shared__ float tile[128 * 101];
    __shared__ float part[8][HW_];
    __shared__ float invp[HW_];
    const int tid = threadIdx.x;
    const int l = tid & 63, wid = tid >> 6;

    {   // norms: wave wid covers c in [wid*80, wid*80+80)
        float s0 = 0.f, s1 = 0.f;
        for (int c = wid * 80; c < wid * 80 + 80; ++c) {
            const float* pc = src + (size_t)c * HW_;
            float x0 = pc[l];
            s0 = fmaf(x0, x0, s0);
            if (l + 64 < HW_) { float x1 = pc[l + 64]; s1 = fmaf(x1, x1, s1); }
        }
        part[wid][l] = s0;
        if (l + 64 < HW_) part[wid][l + 64] = s1;
    }
    __syncthreads();
    if (tid < HW_) {
        float s = 0.f;
        #pragma unroll
        for (int g = 0; g < 8; ++g) s += part[g][tid];
        invp[tid] = 1.f / fmaxf(sqrtf(s), EPSN);
    }
    __syncthreads();

    for (int c0 = 0; c0 < C_; c0 += 128) {
        const float4* s4 = (const float4*)(src + (size_t)c0 * HW_);
        for (int j = tid; j < 3200; j += 512) {
            float4 v = s4[j];
            int f = j * 4;
            int c = f / 100, p = f - c * 100;
            float* d = &tile[c * 101 + p];
            d[0] = v.x; d[1] = v.y; d[2] = v.z; d[3] = v.w;
        }
        __syncthreads();
        for (int j = tid; j < 6400; j += 512) {
            int p  = j >> 6;
            int cl = (j & 63) * 2;
            float iv = invp[p];
            bf16x2 v;
            v.x = (bf16_t)(tile[cl * 101 + p] * iv);
            v.y = (bf16_t)(tile[(cl + 1) * 101 + p] * iv);
            *(bf16x2*)(dst + (size_t)p * C_ + c0 + cl) = v;
        }
        __syncthreads();
    }
}

// ---------------------------------------------------------------------------
// Main MFMA kernel: per (row-tile, t, w): rel tile (64 x 512[500]) over K=640,
// fused per-row top-3 + atomicAdd into score.
// 512 threads = 8 waves, wave tile 64x64 (4 M-frags x 4 N-frags) -> acc 64
// VGPR/wave so 4 waves/SIMD fit (16 waves/CU, 2 blocks). 2-phase dbuf.
// ---------------------------------------------------------------------------
__global__ __launch_bounds__(512, 4) void dn4_mfma(const bf16_t* __restrict__ Qn,
                                                   const bf16_t* __restrict__ Sn,
                                                   float* __restrict__ score) {
    __shared__ bf16_t As[2][64 * 32];        // 8 KB
    __shared__ bf16_t Bs[2][512 * 32];       // 64 KB
    __shared__ float  topL[64][8][3];        // 6 KB   (total 78 KB, 2 blocks/CU)

    const int t = blockIdx.y, w = blockIdx.z;
    const int rbase = blockIdx.x * 64;
    const int tid = threadIdx.x;
    const int l = tid & 63, wid = tid >> 6;  // 8 waves
    const int fr = l & 15, fq = l >> 4;

    const bf16_t* Qt = Qn + (size_t)t * ROWS_ * C_;
    const bf16_t* St = Sn + ((size_t)t * 2500 + (size_t)w * SHW_) * C_;

    // ---- staging addressing ----
    // slot swizzle is (l&3)^((l>>3)&3) for both A and B (row>>1 &3 == (l>>3)&3)
    const int swz = (l & 3) ^ ((l >> 3) & 3);

    // A: waves 0..3 stage rows wid*16..+15 (one gld16 each)
    const int arow = (wid & 3) * 16 + (l >> 2);
    int agr = rbase + arow; if (agr > ROWS_ - 1) agr = ROWS_ - 1;
    const bf16_t* asrc = Qt + (size_t)agr * C_ + swz * 8;

    // B: all 8 waves, 4 rounds; round j covers rows j*128 + wid*16 + (l>>2)
    int bgo[4];
    #pragma unroll
    for (int j = 0; j < 4; ++j) {
        int n = j * 128 + wid * 16 + (l >> 2);
        if (n > SHW_ - 1) n = SHW_ - 1;
        bgo[j] = n * C_ + swz * 8;
    }

    // ---- fragment LDS offsets (kt-invariant) ----
    // read slot = fq ^ ((fr>>1)&3) for both A and B
    const int rslot = fq ^ ((fr >> 1) & 3);
    int aoff[4], boff[4];
    #pragma unroll
    for (int mi = 0; mi < 4; ++mi)
        aoff[mi] = (mi * 16 + fr) * 32 + rslot * 8;
    #pragma unroll
    for (int ni = 0; ni < 4; ++ni)
        boff[ni] = (wid * 64 + ni * 16 + fr) * 32 + rslot * 8;

    f32x4 acc[4][4];
    #pragma unroll
    for (int mi = 0; mi < 4; ++mi)
        #pragma unroll
        for (int ni = 0; ni < 4; ++ni)
            acc[mi][ni] = (f32x4){0.f, 0.f, 0.f, 0.f};

    // prologue: stage tile 0 into buf 0
    if (wid < 4) gld16(asrc, As[0] + wid * 512);
    #pragma unroll
    for (int j = 0; j < 4; ++j)
        gld16(St + bgo[j], Bs[0] + (j * 128 + wid * 16) * 32);
    __syncthreads();

    int cur = 0;
    for (int kt = 0; kt < C_ / 32; ++kt) {
        if (kt + 1 < C_ / 32) {
            const int ko = (kt + 1) * 32;
            if (wid < 4) gld16(asrc + ko, As[cur ^ 1] + wid * 512);
            #pragma unroll
            for (int j = 0; j < 4; ++j)
                gld16(St + bgo[j] + ko, Bs[cur ^ 1] + (j * 128 + wid * 16) * 32);
        }

        bf16x8 av[4], bv[4];
        #pragma unroll
        for (int mi = 0; mi < 4; ++mi)
            av[mi] = *(const bf16x8*)(As[cur] + aoff[mi]);
        #pragma unroll
        for (int ni = 0; ni < 4; ++ni)
            bv[ni] = *(const bf16x8*)(Bs[cur] + boff[ni]);

        #pragma unroll
        for (int mi = 0; mi < 4; ++mi)
            #pragma unroll
            for (int ni = 0; ni < 4; ++ni)
                acc[mi][ni] = __builtin_amdgcn_mfma_f32_16x16x32_bf16(
                    av[mi], bv[ni], acc[mi][ni], 0, 0, 0);

        __syncthreads();   // drains prefetch + readers done
        cur ^= 1;
    }

    // ---- fused top-3 epilogue ----
    // C/D layout: col = wid*64 + ni*16 + fr, row = mi*16 + fq*4 + j
    #pragma unroll
    for (int mi = 0; mi < 4; ++mi) {
        #pragma unroll
        for (int j = 0; j < 4; ++j) {
            float t1 = NINF, t2 = NINF, t3 = NINF;
            #pragma unroll
            for (int ni = 0; ni < 4; ++ni) {
                int gc = wid * 64 + ni * 16 + fr;
                float v = (gc < SHW_) ? acc[mi][ni][j] : NINF;
                float m1 = fmaxf(t1, v),  n1 = fminf(t1, v);
                float m2 = fmaxf(t2, n1), n2 = fminf(t2, n1);
                t1 = m1; t2 = m2; t3 = fmaxf(t3, n2);
            }
            #pragma unroll
            for (int d = 1; d < 16; d <<= 1) {
                float b1 = __shfl_xor(t1, d);
                float b2 = __shfl_xor(t2, d);
                float b3 = __shfl_xor(t3, d);
                MERGE3(t1, t2, t3, b1, b2, b3);
            }
            if (fr == 0) {
                int lrow = mi * 16 + fq * 4 + j;
                topL[lrow][wid][0] = t1;
                topL[lrow][wid][1] = t2;
                topL[lrow][wid][2] = t3;
            }
        }
    }
    __syncthreads();

    if (tid < 64) {
        float a1 = topL[tid][0][0], a2 = topL[tid][0][1], a3 = topL[tid][0][2];
        #pragma unroll
        for (int g = 1; g < 8; ++g) {
            float b1 = topL[tid][g][0], b2 = topL[tid][g][1], b3 = topL[tid][g][2];
            MERGE3(a1, a2, a3, b1, b2, b3);
        }
        int r = rbase + tid;
        if (r < ROWS_) {
            int q = r / 100;
            atomicAdd(score + ((size_t)(t * WQ_ + q) * WAY_ + w), a1 + a2 + a3);
        }
    }
}

// ---------------------------------------------------------------------------
extern "C" void kernel_launch(void* const* d_in, const int* in_sizes, int n_in,
                              void* d_out, int out_size, void* d_ws, size_t ws_size,
                              hipStream_t stream) {
    const float* query   = (const float*)d_in[0];   // (8,75,640,10,10)
    const float* support = (const float*)d_in[1];   // (8,25,640,10,10)
    bf16_t* Qn = (bf16_t*)d_ws;                     // 60000 x 640 bf16 = 76.8 MB
    bf16_t* Sn = Qn + (size_t)T_ * ROWS_ * C_;      // 20000 x 640 bf16 = 25.6 MB
    float* score = (float*)d_out;                   // 8*75*5

    hipMemsetAsync(d_out, 0, (size_t)out_size * sizeof(float), stream);

    hipLaunchKernelGGL(qprep, dim3(T_ * WQ_), dim3(512), 0, stream, query, Qn);
    hipLaunchKernelGGL(sprep, dim3(T_ * 25), dim3(512), 0, stream, support, Sn);
    hipLaunchKernelGGL(dn4_mfma, dim3((ROWS_ + 63) / 64, T_, WAY_), dim3(512),
                       0, stream, Qn, Sn, score);
}